// Round 3
// baseline (1390.314 us; speedup 1.0000x reference)
//
#include <hip/hip_runtime.h>
#include <math.h>

#define NEG_INF (-__builtin_inff())

__device__ __forceinline__ float silu_f(float y) {
    return y / (1.f + __expf(-y));
}

// ---------------- CSR build ----------------

__global__ void k_count(const int* __restrict__ ei, int* __restrict__ cnt, int E) {
    int e = blockIdx.x * 256 + threadIdx.x;
    if (e < E) atomicAdd(&cnt[ei[E + e]], 1);
}

__global__ void k_scanA(const int* __restrict__ cnt, int* __restrict__ bsum, int N) {
    __shared__ int sh[4];
    int i = blockIdx.x * 256 + threadIdx.x;
    int v = (i < N) ? cnt[i] : 0;
#pragma unroll
    for (int m = 1; m < 64; m <<= 1) v += __shfl_xor(v, m, 64);
    int w = threadIdx.x >> 6;
    if ((threadIdx.x & 63) == 0) sh[w] = v;
    __syncthreads();
    if (threadIdx.x == 0) bsum[blockIdx.x] = sh[0] + sh[1] + sh[2] + sh[3];
}

__global__ void k_scanB(const int* __restrict__ bsum, int* __restrict__ boff,
                        int* __restrict__ off, int nb, int N) {
    int lane = threadIdx.x & 63;
    int run = 0;
    for (int base = 0; base < nb; base += 64) {
        int i = base + lane;
        int ov = (i < nb) ? bsum[i] : 0;
        int v = ov;
#pragma unroll
        for (int s = 1; s < 64; s <<= 1) {
            int q = __shfl_up(v, s, 64);
            if (lane >= s) v += q;
        }
        if (i < nb) boff[i] = run + v - ov;
        run += __shfl(v, 63, 64);
    }
    if (lane == 0) off[N] = run;
}

__global__ void k_scanC(const int* __restrict__ cnt, const int* __restrict__ boff,
                        int* __restrict__ off, int N) {
    __shared__ int ls[256];
    int t = threadIdx.x;
    int i = blockIdx.x * 256 + t;
    int myv = (i < N) ? cnt[i] : 0;
    ls[t] = myv;
    __syncthreads();
#pragma unroll
    for (int s = 1; s < 256; s <<= 1) {
        int add = (t >= s) ? ls[t - s] : 0;
        __syncthreads();
        ls[t] += add;
        __syncthreads();
    }
    if (i < N) off[i] = boff[blockIdx.x] + ls[t] - myv;
}

__global__ void k_fill(const int* __restrict__ ei, const int* __restrict__ off,
                       int* __restrict__ cur, int* __restrict__ csr, int E) {
    int e = blockIdx.x * 256 + threadIdx.x;
    if (e < E) {
        int d = ei[E + e];
        int pos = off[d] + atomicAdd(&cur[d], 1);
        csr[pos] = ei[e];
    }
}

// ---------------- Prep: transposed / folded weights ----------------
// wt_sage[l][o][c] (c: 0..127 = Wl rows, 128..191 = Wr rows)
// w1t[j][c] = mlp_W1[c][j];  g2[j][o] = mlp_g[j]*mlp_W2[j][o]
// k12[o] = sum_j bn_j*W2[j][o] + b2[o];  k12[64+o] = sum_j g_j*W2[j][o]

__global__ void k_prep(const float* __restrict__ Wl, const float* __restrict__ Wr,
                       const float* __restrict__ mW1, const float* __restrict__ mg,
                       const float* __restrict__ mbn, const float* __restrict__ mW2,
                       const float* __restrict__ mb2,
                       float* __restrict__ wt_sage, float* __restrict__ w1t,
                       float* __restrict__ g2, float* __restrict__ k12)
{
    int b = blockIdx.x, t = threadIdx.x;
    if (b < 3) {
        int o = t & 63, q = t >> 6;
        for (int c = q * 48; c < q * 48 + 48; ++c) {
            float v = (c < 128) ? Wl[((b * 128) + c) * 64 + o]
                                : Wr[((b * 64) + (c - 128)) * 64 + o];
            wt_sage[((b * 64) + o) * 192 + c] = v;
        }
    } else if (b == 3) {
        for (int c = 0; c < 64; ++c) w1t[t * 64 + c] = mW1[c * 256 + t];
    } else if (b == 4 || b == 5) {
        int base = (b - 4) * 8192;
        for (int i = base + t; i < base + 8192; i += 256)
            g2[i] = mg[i >> 6] * mW2[i];
    } else if (b == 6 && t < 64) {
        float a1 = 0.f, a2 = 0.f;
        for (int j = 0; j < 256; ++j) {
            a1 += mbn[j] * mW2[j * 64 + t];
            a2 += mg[j]  * mW2[j * 64 + t];
        }
        k12[t] = a1 + mb2[t];
        k12[64 + t] = a2;
    }
}

// ---------------- Layer 0 (N_IN=4), one thread per node ----------------

__global__ __launch_bounds__(256, 4)
void k_layer0(const float* __restrict__ x, float* __restrict__ hout,
              const int* __restrict__ off, const int* __restrict__ csr,
              const float* __restrict__ Wl0, const float* __restrict__ bl0,
              const float* __restrict__ Wr0, const float* __restrict__ Wres,
              const float* __restrict__ bres, const float* __restrict__ lg,
              const float* __restrict__ lb, int N)
{
    __shared__ float sWl[512], sWr[256], sWres[256], sC[256];
    int t = threadIdx.x;
    sWl[t] = Wl0[t]; sWl[256 + t] = Wl0[256 + t];
    sWr[t] = Wr0[t];
    sWres[t] = Wres[t];
    if (t < 64) { sC[t] = bl0[t]; sC[64 + t] = bres[t]; sC[128 + t] = lg[t]; sC[192 + t] = lb[t]; }
    __syncthreads();
    int v = blockIdx.x * 256 + t;
    if (v >= N) return;
    const float4* X4 = reinterpret_cast<const float4*>(x);
    float4 xv = X4[v];
    int s0 = off[v], s1 = off[v + 1];
    float4 mx = {NEG_INF, NEG_INF, NEG_INF, NEG_INF};
    float4 sm = {0.f, 0.f, 0.f, 0.f};
    for (int e = s0; e < s1; e += 4) {
        int last = s1 - 1;
        int i0 = csr[e];
        int i1 = csr[min(e + 1, last)];
        int i2 = csr[min(e + 2, last)];
        int i3 = csr[min(e + 3, last)];
        float4 a0 = X4[i0], a1 = X4[i1], a2 = X4[i2], a3 = X4[i3];
        mx.x = fmaxf(fmaxf(fmaxf(mx.x, a0.x), fmaxf(a1.x, a2.x)), a3.x);
        mx.y = fmaxf(fmaxf(fmaxf(mx.y, a0.y), fmaxf(a1.y, a2.y)), a3.y);
        mx.z = fmaxf(fmaxf(fmaxf(mx.z, a0.z), fmaxf(a1.z, a2.z)), a3.z);
        mx.w = fmaxf(fmaxf(fmaxf(mx.w, a0.w), fmaxf(a1.w, a2.w)), a3.w);
        bool o1 = e + 1 < s1, o2 = e + 2 < s1, o3 = e + 3 < s1;
        sm.x += a0.x + (o1 ? a1.x : 0.f) + (o2 ? a2.x : 0.f) + (o3 ? a3.x : 0.f);
        sm.y += a0.y + (o1 ? a1.y : 0.f) + (o2 ? a2.y : 0.f) + (o3 ? a3.y : 0.f);
        sm.z += a0.z + (o1 ? a1.z : 0.f) + (o2 ? a2.z : 0.f) + (o3 ? a3.z : 0.f);
        sm.w += a0.w + (o1 ? a1.w : 0.f) + (o2 ? a2.w : 0.f) + (o3 ? a3.w : 0.f);
    }
    int deg = s1 - s0;
    if (deg == 0) { mx.x = 0.f; mx.y = 0.f; mx.z = 0.f; mx.w = 0.f; }
    float inv = 1.f / (float)max(deg, 1);
    float4 mn = {sm.x * inv, sm.y * inv, sm.z * inv, sm.w * inv};
    float a[64];
    float acc1 = 0.f, acc2 = 0.f;
#pragma unroll
    for (int k = 0; k < 64; ++k) {
        float tv = sC[k]
            + mx.x * sWl[k]       + mx.y * sWl[64 + k]  + mx.z * sWl[128 + k] + mx.w * sWl[192 + k]
            + mn.x * sWl[256 + k] + mn.y * sWl[320 + k] + mn.z * sWl[384 + k] + mn.w * sWl[448 + k]
            + xv.x * sWr[k]       + xv.y * sWr[64 + k]  + xv.z * sWr[128 + k] + xv.w * sWr[192 + k];
        a[k] = tv; acc1 += tv; acc2 += tv * tv;
    }
    float mu = acc1 * (1.f / 64.f);
    float var = acc2 * (1.f / 64.f) - mu * mu;
    float rs = rsqrtf(var + 1e-5f);
    float* orow = hout + (size_t)v * 64;
#pragma unroll
    for (int k = 0; k < 64; ++k) {
        float res = sC[64 + k] + xv.x * sWres[k] + xv.y * sWres[64 + k]
                  + xv.z * sWres[128 + k] + xv.w * sWres[192 + k];
        float y = (a[k] - mu) * rs * sC[128 + k] + sC[192 + k] + res;
        orow[k] = silu_f(y);
    }
}

// ---------------- k_agg: gather + aggregate only (high occupancy) ----------------
// writes aggws[node][0..63]=max, [64..127]=mean

__global__ __launch_bounds__(256, 8)
void k_agg(const float* __restrict__ hin, float* __restrict__ aggws,
           const int* __restrict__ off, const int* __restrict__ csr, int N)
{
    int lane = threadIdx.x & 63;
    int gw = (blockIdx.x * blockDim.x + threadIdx.x) >> 6;
    int nw = (gridDim.x * blockDim.x) >> 6;
    for (int v = gw; v < N; v += nw) {
        int s0 = off[v], s1 = off[v + 1];
        float mx = NEG_INF, sm = 0.f;
        for (int cb = s0; cb < s1; cb += 64) {
            int cdeg = min(64, s1 - cb);
            int idxv = csr[min(cb + lane, s1 - 1)];
            for (int b = 0; b < cdeg; b += 8) {
                float vv[8];
#pragma unroll
                for (int u = 0; u < 8; ++u) {
                    int iu = __builtin_amdgcn_readlane(idxv, b + u);
                    vv[u] = hin[((size_t)iu << 6) + lane];
                }
#pragma unroll
                for (int u = 0; u < 8; ++u) {
                    mx = fmaxf(mx, vv[u]);                // dup rows don't change max
                    sm += (b + u < cdeg) ? vv[u] : 0.f;   // mask dups out of sum
                }
            }
        }
        int deg = s1 - s0;
        if (deg == 0) mx = 0.f;
        float mean = sm / (float)max(deg, 1);
        aggws[((size_t)v << 7) + lane] = mx;
        aggws[((size_t)v << 7) + 64 + lane] = mean;
    }
}

// ---------------- k_sagemm: transposed matmul+LN+silu (lane = node) ----------------
// t_o = sum_c agg[c]*Wt[o][c] + bl[o];  y = silu(LN(t)*g + b + hs)

__global__ __launch_bounds__(128, 2)
void k_sagemm(const float* __restrict__ aggws, const float* __restrict__ hin,
              float* __restrict__ hout, const float* __restrict__ Wt,
              const float* __restrict__ bl, const float* __restrict__ lg,
              const float* __restrict__ lb, int N)
{
    __shared__ float sst[2][64 * 68];
    int lane = threadIdx.x & 63, w = threadIdx.x >> 6;
    int base = (blockIdx.x * 2 + w) * 64;
    if (base >= N) return;
    int node = base + lane;
    int nclamp = min(node, N - 1);

    float r[192];
    {
        const float4* arow = reinterpret_cast<const float4*>(aggws + ((size_t)nclamp << 7));
        const float4* hrow = reinterpret_cast<const float4*>(hin + ((size_t)nclamp << 6));
#pragma unroll
        for (int k = 0; k < 32; ++k) {
            float4 t4 = arow[k];
            r[4 * k] = t4.x; r[4 * k + 1] = t4.y; r[4 * k + 2] = t4.z; r[4 * k + 3] = t4.w;
        }
#pragma unroll
        for (int k = 0; k < 16; ++k) {
            float4 t4 = hrow[k];
            r[128 + 4 * k] = t4.x; r[128 + 4 * k + 1] = t4.y;
            r[128 + 4 * k + 2] = t4.z; r[128 + 4 * k + 3] = t4.w;
        }
    }
    float* myst = &sst[w][0];
    float acc1 = 0.f, acc2 = 0.f;
    for (int o = 0; o < 64; ++o) {
        const float* wt = Wt + o * 192;      // wave-uniform -> s_load
        float t0 = bl[o], t1 = 0.f, t2 = 0.f, t3 = 0.f;
#pragma unroll
        for (int c = 0; c < 192; c += 4) {
            t0 += r[c] * wt[c];
            t1 += r[c + 1] * wt[c + 1];
            t2 += r[c + 2] * wt[c + 2];
            t3 += r[c + 3] * wt[c + 3];
        }
        float tv = (t0 + t1) + (t2 + t3);
        acc1 += tv; acc2 += tv * tv;
        myst[lane * 68 + o] = tv;
    }
    float mu = acc1 * (1.f / 64.f);
    float var = acc2 * (1.f / 64.f) - mu * mu;
    float rs = rsqrtf(var + 1e-5f);
    bool alive = node < N;
    float* orow = hout + ((size_t)node << 6);
#pragma unroll
    for (int k = 0; k < 16; ++k) {
        float4 tq = *reinterpret_cast<float4*>(&myst[lane * 68 + 4 * k]);
        float4 yv;
        yv.x = silu_f((tq.x - mu) * rs * lg[4 * k]     + lb[4 * k]     + r[128 + 4 * k]);
        yv.y = silu_f((tq.y - mu) * rs * lg[4 * k + 1] + lb[4 * k + 1] + r[128 + 4 * k + 1]);
        yv.z = silu_f((tq.z - mu) * rs * lg[4 * k + 2] + lb[4 * k + 2] + r[128 + 4 * k + 2]);
        yv.w = silu_f((tq.w - mu) * rs * lg[4 * k + 3] + lb[4 * k + 3] + r[128 + 4 * k + 3]);
        if (alive) *reinterpret_cast<float4*>(&orow[4 * k]) = yv;
    }
}

// ---------------- k_mlp: transposed (lane = node), streamed LN-W2 ----------------
// s_j = silu(h . W1t[j] + b1[j]); A[o] += s_j * g2[j][o];
// out[o] = rs*A[o] + K1[o] - rs*mu*K2[o]

__global__ __launch_bounds__(128, 3)
void k_mlp(const float* __restrict__ hin, float* __restrict__ hout,
           const float* __restrict__ W1t, const float* __restrict__ b1,
           const float* __restrict__ G2, const float* __restrict__ K12, int N)
{
    int lane = threadIdx.x & 63, w = threadIdx.x >> 6;
    int base = (blockIdx.x * 2 + w) * 64;
    if (base >= N) return;
    int node = base + lane;
    int nclamp = min(node, N - 1);

    float h[64];
    {
        const float4* hrow = reinterpret_cast<const float4*>(hin + ((size_t)nclamp << 6));
#pragma unroll
        for (int k = 0; k < 16; ++k) {
            float4 t4 = hrow[k];
            h[4 * k] = t4.x; h[4 * k + 1] = t4.y; h[4 * k + 2] = t4.z; h[4 * k + 3] = t4.w;
        }
    }
    float A[64];
#pragma unroll
    for (int o = 0; o < 64; ++o) A[o] = 0.f;
    float acc1 = 0.f, acc2 = 0.f;
    for (int j = 0; j < 256; ++j) {
        const float* w1 = W1t + j * 64;      // wave-uniform -> s_load
        const float* g2 = G2 + j * 64;
        float t0 = b1[j], t1 = 0.f, t2 = 0.f, t3 = 0.f;
#pragma unroll
        for (int c = 0; c < 64; c += 4) {
            t0 += h[c] * w1[c];
            t1 += h[c + 1] * w1[c + 1];
            t2 += h[c + 2] * w1[c + 2];
            t3 += h[c + 3] * w1[c + 3];
        }
        float s = silu_f((t0 + t1) + (t2 + t3));
        acc1 += s; acc2 += s * s;
#pragma unroll
        for (int o = 0; o < 64; ++o) A[o] += s * g2[o];
    }
    float mu = acc1 * (1.f / 256.f);
    float var = acc2 * (1.f / 256.f) - mu * mu;
    float rs = rsqrtf(var + 1e-5f);
    float rm = rs * mu;
    bool alive = node < N;
    float* orow = hout + ((size_t)node << 6);
#pragma unroll
    for (int k = 0; k < 16; ++k) {
        float4 yv;
        yv.x = rs * A[4 * k]     + K12[4 * k]     - rm * K12[64 + 4 * k];
        yv.y = rs * A[4 * k + 1] + K12[4 * k + 1] - rm * K12[64 + 4 * k + 1];
        yv.z = rs * A[4 * k + 2] + K12[4 * k + 2] - rm * K12[64 + 4 * k + 2];
        yv.w = rs * A[4 * k + 3] + K12[4 * k + 3] - rm * K12[64 + 4 * k + 3];
        if (alive) *reinterpret_cast<float4*>(&orow[4 * k]) = yv;
    }
}

// ---------------- Readout: block per graph ----------------

__global__ __launch_bounds__(256, 2)
void k_readout(const float* __restrict__ h2, const float* __restrict__ x,
               const int* __restrict__ ptr,
               const float* __restrict__ W1, const float* __restrict__ b1,
               const float* __restrict__ lg, const float* __restrict__ lb,
               const float* __restrict__ W2, const float* __restrict__ b2,
               float* __restrict__ out)
{
    __shared__ float f[196];
    __shared__ float sred[4][64];
    __shared__ float mred[4][64];
    __shared__ float lred[8];
    __shared__ float pr[4][4];
    int t = threadIdx.x, lane = t & 63, w = t >> 6;
    int g = blockIdx.x;
    int s0 = ptr[g], s1 = ptr[g + 1];
    float sm = 0.f, mx = NEG_INF;
    for (int r = s0 + w; r < s1; r += 4) {
        float v = h2[(size_t)r * 64 + lane];
        sm += v; mx = fmaxf(mx, v);
    }
    sred[w][lane] = sm; mred[w][lane] = mx;
    __syncthreads();
    if (w == 0) {
        float ssum = sred[0][lane] + sred[1][lane] + sred[2][lane] + sred[3][lane];
        float smax = fmaxf(fmaxf(mred[0][lane], mred[1][lane]),
                           fmaxf(mred[2][lane], mred[3][lane]));
        int cnt = s1 - s0;
        if (cnt == 0) smax = 0.f;
        f[lane] = ssum / (float)max(cnt, 1);
        f[64 + lane] = smax;
        f[128 + lane] = ssum;
    }
    if (t < 4) f[192 + t] = x[(size_t)s0 * 4 + t];
    __syncthreads();
    float o = b1[t];
    for (int c = 0; c < 196; ++c) o += f[c] * W1[c * 256 + t];
    o = silu_f(o);
    float s = o, s2v = o * o;
#pragma unroll
    for (int m = 1; m < 64; m <<= 1) { s += __shfl_xor(s, m, 64); s2v += __shfl_xor(s2v, m, 64); }
    if (lane == 0) { lred[w] = s; lred[4 + w] = s2v; }
    __syncthreads();
    float tot = lred[0] + lred[1] + lred[2] + lred[3];
    float tot2 = lred[4] + lred[5] + lred[6] + lred[7];
    float mu = tot * (1.f / 256.f);
    float var = tot2 * (1.f / 256.f) - mu * mu;
    float u = (o - mu) * rsqrtf(var + 1e-5f) * lg[t] + lb[t];
    float4 w2r = reinterpret_cast<const float4*>(W2)[t];
    float p0 = u * w2r.x, p1 = u * w2r.y, p2 = u * w2r.z, p3 = u * w2r.w;
#pragma unroll
    for (int m = 1; m < 64; m <<= 1) {
        p0 += __shfl_xor(p0, m, 64); p1 += __shfl_xor(p1, m, 64);
        p2 += __shfl_xor(p2, m, 64); p3 += __shfl_xor(p3, m, 64);
    }
    if (lane == 0) { pr[w][0] = p0; pr[w][1] = p1; pr[w][2] = p2; pr[w][3] = p3; }
    __syncthreads();
    if (t < 4) out[g * 4 + t] = pr[0][t] + pr[1][t] + pr[2][t] + pr[3][t] + b2[t];
}

// ---------------- launch ----------------

extern "C" void kernel_launch(void* const* d_in, const int* in_sizes, int n_in,
                              void* d_out, int out_size, void* d_ws, size_t ws_size,
                              hipStream_t stream)
{
    const float* x    = (const float*)d_in[0];
    const int*   ei   = (const int*)d_in[1];
    const int*   ptr  = (const int*)d_in[3];
    const float* Wl0  = (const float*)d_in[4];
    const float* bl0  = (const float*)d_in[5];
    const float* Wr0  = (const float*)d_in[6];
    const float* Wl   = (const float*)d_in[7];
    const float* bl   = (const float*)d_in[8];
    const float* Wr   = (const float*)d_in[9];
    const float* Wres = (const float*)d_in[10];
    const float* bres = (const float*)d_in[11];
    const float* lng  = (const float*)d_in[12];
    const float* lnb  = (const float*)d_in[13];
    const float* mW1  = (const float*)d_in[14];
    const float* mb1  = (const float*)d_in[15];
    const float* mg   = (const float*)d_in[16];
    const float* mbn  = (const float*)d_in[17];
    const float* mW2  = (const float*)d_in[18];
    const float* mb2  = (const float*)d_in[19];
    const float* rW1  = (const float*)d_in[20];
    const float* rb1  = (const float*)d_in[21];
    const float* rg   = (const float*)d_in[22];
    const float* rbn  = (const float*)d_in[23];
    const float* rW2  = (const float*)d_in[24];
    const float* rb2  = (const float*)d_in[25];
    float* out = (float*)d_out;

    int N = in_sizes[0] / 4;
    int E = in_sizes[1] / 2;
    int NG = in_sizes[3] - 1;
    int nchunk = (N + 255) / 256;
    int neblk  = (E + 255) / 256;
    int nwv    = (N + 63) / 64;          // waves for transposed kernels
    int gtr    = (nwv + 1) / 2;          // 128-thread blocks, 2 waves each

    char* ws = (char*)d_ws;
    size_t o = 0;
    auto alloc = [&](size_t bytes) -> void* {
        void* p = ws + o;
        o += (bytes + 255) & ~(size_t)255;
        return p;
    };
    int*   off    = (int*)alloc((size_t)(N + 1) * 4);
    int*   cnt    = (int*)alloc((size_t)N * 4);
    int*   cur    = (int*)alloc((size_t)N * 4);
    int*   bsum   = (int*)alloc((size_t)nchunk * 4);
    int*   boff   = (int*)alloc((size_t)nchunk * 4);
    int*   csr    = (int*)alloc((size_t)E * 4);
    float* ha     = (float*)alloc((size_t)N * 64 * 4);
    float* hb     = (float*)alloc((size_t)N * 64 * 4);
    float* aggws  = (float*)alloc((size_t)N * 128 * 4);
    float* wtsage = (float*)alloc((size_t)3 * 64 * 192 * 4);
    float* w1t    = (float*)alloc((size_t)256 * 64 * 4);
    float* g2     = (float*)alloc((size_t)256 * 64 * 4);
    float* k12    = (float*)alloc((size_t)128 * 4);

    hipMemsetAsync(cnt, 0, (size_t)N * 4, stream);
    hipMemsetAsync(cur, 0, (size_t)N * 4, stream);
    k_prep<<<7, 256, 0, stream>>>(Wl, Wr, mW1, mg, mbn, mW2, mb2, wtsage, w1t, g2, k12);
    k_count<<<neblk, 256, 0, stream>>>(ei, cnt, E);
    k_scanA<<<nchunk, 256, 0, stream>>>(cnt, bsum, N);
    k_scanB<<<1, 64, 0, stream>>>(bsum, boff, off, nchunk, N);
    k_scanC<<<nchunk, 256, 0, stream>>>(cnt, boff, off, N);
    k_fill<<<neblk, 256, 0, stream>>>(ei, off, cur, csr, E);

    k_layer0<<<nchunk, 256, 0, stream>>>(x, ha, off, csr, Wl0, bl0, Wr0, Wres, bres, lng, lnb, N);

    k_agg<<<2048, 256, 0, stream>>>(ha, aggws, off, csr, N);
    k_sagemm<<<gtr, 128, 0, stream>>>(aggws, ha, hb, wtsage,            bl,       lng + 64,  lnb + 64,  N);
    k_agg<<<2048, 256, 0, stream>>>(hb, aggws, off, csr, N);
    k_sagemm<<<gtr, 128, 0, stream>>>(aggws, hb, ha, wtsage + 64 * 192, bl + 64,  lng + 128, lnb + 128, N);
    k_agg<<<2048, 256, 0, stream>>>(ha, aggws, off, csr, N);
    k_sagemm<<<gtr, 128, 0, stream>>>(aggws, ha, hb, wtsage + 2 * 64 * 192, bl + 128, lng + 192, lnb + 192, N);

    k_mlp<<<gtr, 128, 0, stream>>>(hb, ha, w1t, mb1, g2, k12, N);
    k_readout<<<NG, 256, 0, stream>>>(ha, x, ptr, rW1, rb1, rg, rbn, rW2, rb2, out);
}

// Round 4
// 1052.066 us; speedup vs baseline: 1.3215x; 1.3215x over previous
//
#include <hip/hip_runtime.h>
#include <math.h>

#define NEG_INF (-__builtin_inff())

__device__ __forceinline__ float rlane(float x, int l) {
    return __int_as_float(__builtin_amdgcn_readlane(__float_as_int(x), l));
}

__device__ __forceinline__ float silu_f(float y) {
    return y / (1.f + __expf(-y));
}

// ---------------- CSR build ----------------

__global__ void k_count(const int* __restrict__ ei, int* __restrict__ cnt, int E) {
    int e = blockIdx.x * 256 + threadIdx.x;
    if (e < E) atomicAdd(&cnt[ei[E + e]], 1);
}

__global__ void k_scanA(const int* __restrict__ cnt, int* __restrict__ bsum, int N) {
    __shared__ int sh[4];
    int i = blockIdx.x * 256 + threadIdx.x;
    int v = (i < N) ? cnt[i] : 0;
#pragma unroll
    for (int m = 1; m < 64; m <<= 1) v += __shfl_xor(v, m, 64);
    int w = threadIdx.x >> 6;
    if ((threadIdx.x & 63) == 0) sh[w] = v;
    __syncthreads();
    if (threadIdx.x == 0) bsum[blockIdx.x] = sh[0] + sh[1] + sh[2] + sh[3];
}

__global__ void k_scanB(const int* __restrict__ bsum, int* __restrict__ boff,
                        int* __restrict__ off, int nb, int N) {
    int lane = threadIdx.x & 63;
    int run = 0;
    for (int base = 0; base < nb; base += 64) {
        int i = base + lane;
        int ov = (i < nb) ? bsum[i] : 0;
        int v = ov;
#pragma unroll
        for (int s = 1; s < 64; s <<= 1) {
            int q = __shfl_up(v, s, 64);
            if (lane >= s) v += q;
        }
        if (i < nb) boff[i] = run + v - ov;
        run += __shfl(v, 63, 64);
    }
    if (lane == 0) off[N] = run;
}

__global__ void k_scanC(const int* __restrict__ cnt, const int* __restrict__ boff,
                        int* __restrict__ off, int N) {
    __shared__ int ls[256];
    int t = threadIdx.x;
    int i = blockIdx.x * 256 + t;
    int myv = (i < N) ? cnt[i] : 0;
    ls[t] = myv;
    __syncthreads();
#pragma unroll
    for (int s = 1; s < 256; s <<= 1) {
        int add = (t >= s) ? ls[t - s] : 0;
        __syncthreads();
        ls[t] += add;
        __syncthreads();
    }
    if (i < N) off[i] = boff[blockIdx.x] + ls[t] - myv;
}

__global__ void k_fill(const int* __restrict__ ei, const int* __restrict__ off,
                       int* __restrict__ cur, int* __restrict__ csr, int E) {
    int e = blockIdx.x * 256 + threadIdx.x;
    if (e < E) {
        int d = ei[E + e];
        int pos = off[d] + atomicAdd(&cur[d], 1);
        csr[pos] = ei[e];
    }
}

// ---------------- Layer 0 (N_IN=4), one thread per node ----------------

__global__ __launch_bounds__(256, 4)
void k_layer0(const float* __restrict__ x, float* __restrict__ hout,
              const int* __restrict__ off, const int* __restrict__ csr,
              const float* __restrict__ Wl0, const float* __restrict__ bl0,
              const float* __restrict__ Wr0, const float* __restrict__ Wres,
              const float* __restrict__ bres, const float* __restrict__ lg,
              const float* __restrict__ lb, int N)
{
    __shared__ float sWl[512], sWr[256], sWres[256], sC[256];
    int t = threadIdx.x;
    sWl[t] = Wl0[t]; sWl[256 + t] = Wl0[256 + t];
    sWr[t] = Wr0[t];
    sWres[t] = Wres[t];
    if (t < 64) { sC[t] = bl0[t]; sC[64 + t] = bres[t]; sC[128 + t] = lg[t]; sC[192 + t] = lb[t]; }
    __syncthreads();
    int v = blockIdx.x * 256 + t;
    if (v >= N) return;
    const float4* X4 = reinterpret_cast<const float4*>(x);
    float4 xv = X4[v];
    int s0 = off[v], s1 = off[v + 1];
    float4 mx = {NEG_INF, NEG_INF, NEG_INF, NEG_INF};
    float4 sm = {0.f, 0.f, 0.f, 0.f};
    for (int e = s0; e < s1; e += 4) {
        int last = s1 - 1;
        int i0 = csr[e];
        int i1 = csr[min(e + 1, last)];
        int i2 = csr[min(e + 2, last)];
        int i3 = csr[min(e + 3, last)];
        float4 a0 = X4[i0], a1 = X4[i1], a2 = X4[i2], a3 = X4[i3];
        mx.x = fmaxf(fmaxf(fmaxf(mx.x, a0.x), fmaxf(a1.x, a2.x)), a3.x);
        mx.y = fmaxf(fmaxf(fmaxf(mx.y, a0.y), fmaxf(a1.y, a2.y)), a3.y);
        mx.z = fmaxf(fmaxf(fmaxf(mx.z, a0.z), fmaxf(a1.z, a2.z)), a3.z);
        mx.w = fmaxf(fmaxf(fmaxf(mx.w, a0.w), fmaxf(a1.w, a2.w)), a3.w);
        bool o1 = e + 1 < s1, o2 = e + 2 < s1, o3 = e + 3 < s1;
        sm.x += a0.x + (o1 ? a1.x : 0.f) + (o2 ? a2.x : 0.f) + (o3 ? a3.x : 0.f);
        sm.y += a0.y + (o1 ? a1.y : 0.f) + (o2 ? a2.y : 0.f) + (o3 ? a3.y : 0.f);
        sm.z += a0.z + (o1 ? a1.z : 0.f) + (o2 ? a2.z : 0.f) + (o3 ? a3.z : 0.f);
        sm.w += a0.w + (o1 ? a1.w : 0.f) + (o2 ? a2.w : 0.f) + (o3 ? a3.w : 0.f);
    }
    int deg = s1 - s0;
    if (deg == 0) { mx.x = 0.f; mx.y = 0.f; mx.z = 0.f; mx.w = 0.f; }
    float inv = 1.f / (float)max(deg, 1);
    float4 mn = {sm.x * inv, sm.y * inv, sm.z * inv, sm.w * inv};
    float a[64];
    float acc1 = 0.f, acc2 = 0.f;
#pragma unroll
    for (int k = 0; k < 64; ++k) {
        float tv = sC[k]
            + mx.x * sWl[k]       + mx.y * sWl[64 + k]  + mx.z * sWl[128 + k] + mx.w * sWl[192 + k]
            + mn.x * sWl[256 + k] + mn.y * sWl[320 + k] + mn.z * sWl[384 + k] + mn.w * sWl[448 + k]
            + xv.x * sWr[k]       + xv.y * sWr[64 + k]  + xv.z * sWr[128 + k] + xv.w * sWr[192 + k];
        a[k] = tv; acc1 += tv; acc2 += tv * tv;
    }
    float mu = acc1 * (1.f / 64.f);
    float var = acc2 * (1.f / 64.f) - mu * mu;
    float rs = rsqrtf(var + 1e-5f);
    float* orow = hout + (size_t)v * 64;
#pragma unroll
    for (int k = 0; k < 64; ++k) {
        float res = sC[64 + k] + xv.x * sWres[k] + xv.y * sWres[64 + k]
                  + xv.z * sWres[128 + k] + xv.w * sWres[192 + k];
        float y = (a[k] - mu) * rs * sC[128 + k] + sC[192 + k] + res;
        orow[k] = silu_f(y);
    }
}

// ---------------- k_agg: gather + aggregate only (high occupancy) ----------------
// writes aggws[node][0..63]=max, [64..127]=mean

__global__ __launch_bounds__(256, 8)
void k_agg(const float* __restrict__ hin, float* __restrict__ aggws,
           const int* __restrict__ off, const int* __restrict__ csr, int N)
{
    int lane = threadIdx.x & 63;
    int gw = (blockIdx.x * blockDim.x + threadIdx.x) >> 6;
    int nw = (gridDim.x * blockDim.x) >> 6;
    for (int v = gw; v < N; v += nw) {
        int s0 = off[v], s1 = off[v + 1];
        float mx = NEG_INF, sm = 0.f;
        for (int cb = s0; cb < s1; cb += 64) {
            int cdeg = min(64, s1 - cb);
            int idxv = csr[min(cb + lane, s1 - 1)];
            for (int b = 0; b < cdeg; b += 8) {
                float vv[8];
#pragma unroll
                for (int u = 0; u < 8; ++u) {
                    int iu = __builtin_amdgcn_readlane(idxv, b + u);
                    vv[u] = hin[((size_t)iu << 6) + lane];
                }
#pragma unroll
                for (int u = 0; u < 8; ++u) {
                    mx = fmaxf(mx, vv[u]);                // dup rows don't change max
                    sm += (b + u < cdeg) ? vv[u] : 0.f;   // mask dups out of sum
                }
            }
        }
        int deg = s1 - s0;
        if (deg == 0) mx = 0.f;
        float mean = sm / (float)max(deg, 1);
        aggws[((size_t)v << 7) + lane] = mx;
        aggws[((size_t)v << 7) + 64 + lane] = mean;
    }
}

// ---------------- k_smm: matmul+LN+silu, round-2-proven readlane structure ----------------
// lane = output channel; weight columns in VGPRs (spill-tolerant); inputs
// broadcast via readlane. 3 independent accumulator chains for ILP.

__global__ __launch_bounds__(256, 2)
void k_smm(const float* __restrict__ aggws, const float* __restrict__ hin,
           float* __restrict__ hout,
           const float* __restrict__ Wl, const float* __restrict__ bl,
           const float* __restrict__ Wr, const float* __restrict__ lg,
           const float* __restrict__ lb, int N)
{
    int lane = threadIdx.x & 63;
    int gw = (blockIdx.x * blockDim.x + threadIdx.x) >> 6;
    int nw = (gridDim.x * blockDim.x) >> 6;
    float wl[128], wr[64];
#pragma unroll
    for (int c = 0; c < 128; ++c) wl[c] = Wl[c * 64 + lane];
#pragma unroll
    for (int c = 0; c < 64; ++c) wr[c] = Wr[c * 64 + lane];
    float blv = bl[lane], gv = lg[lane], bv = lb[lane];
    for (int v = gw; v < N; v += nw) {
        float mx   = aggws[((size_t)v << 7) + lane];
        float mean = aggws[((size_t)v << 7) + 64 + lane];
        float hs   = hin[((size_t)v << 6) + lane];
        float a0 = blv, a1 = 0.f, a2 = 0.f;
#pragma unroll
        for (int c = 0; c < 64; ++c) {
            a0 += rlane(mx, c) * wl[c];
            a1 += rlane(mean, c) * wl[64 + c];
            a2 += rlane(hs, c) * wr[c];
        }
        float acc = a0 + a1 + a2;
        float mu = acc;
#pragma unroll
        for (int m = 1; m < 64; m <<= 1) mu += __shfl_xor(mu, m, 64);
        mu *= (1.f / 64.f);
        float xc = acc - mu;
        float var = xc * xc;
#pragma unroll
        for (int m = 1; m < 64; m <<= 1) var += __shfl_xor(var, m, 64);
        var *= (1.f / 64.f);
        float y = xc * rsqrtf(var + 1e-5f) * gv + bv + hs;
        hout[((size_t)v << 6) + lane] = silu_f(y);
    }
}

// ---------------- MLP: round-2 version verbatim (known 277 us) ----------------

__global__ __launch_bounds__(256, 3)
void k_mlp(const float* __restrict__ hin, float* __restrict__ hout,
           const float* __restrict__ W1, const float* __restrict__ b1,
           const float* __restrict__ lg, const float* __restrict__ lb,
           const float* __restrict__ W2, const float* __restrict__ b2, int N)
{
    __shared__ float red[8];
    __shared__ float part[4][64];
    int lane = threadIdx.x & 63;
    int w = threadIdx.x >> 6;
    int kk = (w << 6) + lane;          // channel in [0,256)
    float w1c[64], w2c[64];
#pragma unroll
    for (int c = 0; c < 64; ++c) w1c[c] = W1[c * 256 + kk];
#pragma unroll
    for (int i = 0; i < 64; ++i) w2c[i] = W2[(((w << 6) + i) << 6) + lane];
    float b1v = b1[kk], gv = lg[kk], bnv = lb[kk];
    for (int v = blockIdx.x; v < N; v += gridDim.x) {
        float hreg = hin[(size_t)v * 64 + lane];
        float tv = b1v;
#pragma unroll
        for (int c = 0; c < 64; ++c) tv += rlane(hreg, c) * w1c[c];
        tv = silu_f(tv);
        float s = tv, s2 = tv * tv;
#pragma unroll
        for (int m = 1; m < 64; m <<= 1) { s += __shfl_xor(s, m, 64); s2 += __shfl_xor(s2, m, 64); }
        if (lane == 0) { red[w] = s; red[4 + w] = s2; }
        __syncthreads();
        float tot = red[0] + red[1] + red[2] + red[3];
        float tot2 = red[4] + red[5] + red[6] + red[7];
        float mu = tot * (1.f / 256.f);
        float var = tot2 * (1.f / 256.f) - mu * mu;
        float u = (tv - mu) * rsqrtf(var + 1e-5f) * gv + bnv;
        float p = 0.f;
#pragma unroll
        for (int i = 0; i < 64; ++i) p += rlane(u, i) * w2c[i];
        part[w][lane] = p;
        __syncthreads();
        if (w == 0) {
            float o = part[0][lane] + part[1][lane] + part[2][lane] + part[3][lane] + b2[lane];
            hout[(size_t)v * 64 + lane] = o;
        }
    }
}

// ---------------- Readout: block per graph ----------------

__global__ __launch_bounds__(256, 2)
void k_readout(const float* __restrict__ h2, const float* __restrict__ x,
               const int* __restrict__ ptr,
               const float* __restrict__ W1, const float* __restrict__ b1,
               const float* __restrict__ lg, const float* __restrict__ lb,
               const float* __restrict__ W2, const float* __restrict__ b2,
               float* __restrict__ out)
{
    __shared__ float f[196];
    __shared__ float sred[4][64];
    __shared__ float mred[4][64];
    __shared__ float lred[8];
    __shared__ float pr[4][4];
    int t = threadIdx.x, lane = t & 63, w = t >> 6;
    int g = blockIdx.x;
    int s0 = ptr[g], s1 = ptr[g + 1];
    float sm = 0.f, mx = NEG_INF;
    for (int r = s0 + w; r < s1; r += 4) {
        float v = h2[(size_t)r * 64 + lane];
        sm += v; mx = fmaxf(mx, v);
    }
    sred[w][lane] = sm; mred[w][lane] = mx;
    __syncthreads();
    if (w == 0) {
        float ssum = sred[0][lane] + sred[1][lane] + sred[2][lane] + sred[3][lane];
        float smax = fmaxf(fmaxf(mred[0][lane], mred[1][lane]),
                           fmaxf(mred[2][lane], mred[3][lane]));
        int cnt = s1 - s0;
        if (cnt == 0) smax = 0.f;
        f[lane] = ssum / (float)max(cnt, 1);
        f[64 + lane] = smax;
        f[128 + lane] = ssum;
    }
    if (t < 4) f[192 + t] = x[(size_t)s0 * 4 + t];
    __syncthreads();
    float o = b1[t];
    for (int c = 0; c < 196; ++c) o += f[c] * W1[c * 256 + t];
    o = silu_f(o);
    float s = o, s2v = o * o;
#pragma unroll
    for (int m = 1; m < 64; m <<= 1) { s += __shfl_xor(s, m, 64); s2v += __shfl_xor(s2v, m, 64); }
    if (lane == 0) { lred[w] = s; lred[4 + w] = s2v; }
    __syncthreads();
    float tot = lred[0] + lred[1] + lred[2] + lred[3];
    float tot2 = lred[4] + lred[5] + lred[6] + lred[7];
    float mu = tot * (1.f / 256.f);
    float var = tot2 * (1.f / 256.f) - mu * mu;
    float u = (o - mu) * rsqrtf(var + 1e-5f) * lg[t] + lb[t];
    float4 w2r = reinterpret_cast<const float4*>(W2)[t];
    float p0 = u * w2r.x, p1 = u * w2r.y, p2 = u * w2r.z, p3 = u * w2r.w;
#pragma unroll
    for (int m = 1; m < 64; m <<= 1) {
        p0 += __shfl_xor(p0, m, 64); p1 += __shfl_xor(p1, m, 64);
        p2 += __shfl_xor(p2, m, 64); p3 += __shfl_xor(p3, m, 64);
    }
    if (lane == 0) { pr[w][0] = p0; pr[w][1] = p1; pr[w][2] = p2; pr[w][3] = p3; }
    __syncthreads();
    if (t < 4) out[g * 4 + t] = pr[0][t] + pr[1][t] + pr[2][t] + pr[3][t] + b2[t];
}

// ---------------- launch ----------------

extern "C" void kernel_launch(void* const* d_in, const int* in_sizes, int n_in,
                              void* d_out, int out_size, void* d_ws, size_t ws_size,
                              hipStream_t stream)
{
    const float* x    = (const float*)d_in[0];
    const int*   ei   = (const int*)d_in[1];
    const int*   ptr  = (const int*)d_in[3];
    const float* Wl0  = (const float*)d_in[4];
    const float* bl0  = (const float*)d_in[5];
    const float* Wr0  = (const float*)d_in[6];
    const float* Wl   = (const float*)d_in[7];
    const float* bl   = (const float*)d_in[8];
    const float* Wr   = (const float*)d_in[9];
    const float* Wres = (const float*)d_in[10];
    const float* bres = (const float*)d_in[11];
    const float* lng  = (const float*)d_in[12];
    const float* lnb  = (const float*)d_in[13];
    const float* mW1  = (const float*)d_in[14];
    const float* mb1  = (const float*)d_in[15];
    const float* mg   = (const float*)d_in[16];
    const float* mbn  = (const float*)d_in[17];
    const float* mW2  = (const float*)d_in[18];
    const float* mb2  = (const float*)d_in[19];
    const float* rW1  = (const float*)d_in[20];
    const float* rb1  = (const float*)d_in[21];
    const float* rg   = (const float*)d_in[22];
    const float* rbn  = (const float*)d_in[23];
    const float* rW2  = (const float*)d_in[24];
    const float* rb2  = (const float*)d_in[25];
    float* out = (float*)d_out;

    int N = in_sizes[0] / 4;
    int E = in_sizes[1] / 2;
    int NG = in_sizes[3] - 1;
    int nchunk = (N + 255) / 256;
    int neblk  = (E + 255) / 256;

    char* ws = (char*)d_ws;
    size_t o = 0;
    auto alloc = [&](size_t bytes) -> void* {
        void* p = ws + o;
        o += (bytes + 255) & ~(size_t)255;
        return p;
    };
    int*   off   = (int*)alloc((size_t)(N + 1) * 4);
    int*   cnt   = (int*)alloc((size_t)N * 4);
    int*   cur   = (int*)alloc((size_t)N * 4);
    int*   bsum  = (int*)alloc((size_t)nchunk * 4);
    int*   boff  = (int*)alloc((size_t)nchunk * 4);
    int*   csr   = (int*)alloc((size_t)E * 4);
    float* ha    = (float*)alloc((size_t)N * 64 * 4);
    float* hb    = (float*)alloc((size_t)N * 64 * 4);
    float* aggws = (float*)alloc((size_t)N * 128 * 4);

    // cnt and cur are adjacent in the workspace: one memset covers both
    hipMemsetAsync(cnt, 0, (size_t)((char*)cur - (char*)cnt) + (size_t)N * 4, stream);
    k_count<<<neblk, 256, 0, stream>>>(ei, cnt, E);
    k_scanA<<<nchunk, 256, 0, stream>>>(cnt, bsum, N);
    k_scanB<<<1, 64, 0, stream>>>(bsum, boff, off, nchunk, N);
    k_scanC<<<nchunk, 256, 0, stream>>>(cnt, boff, off, N);
    k_fill<<<neblk, 256, 0, stream>>>(ei, off, cur, csr, E);

    k_layer0<<<nchunk, 256, 0, stream>>>(x, ha, off, csr, Wl0, bl0, Wr0, Wres, bres, lng, lnb, N);

    k_agg<<<2048, 256, 0, stream>>>(ha, aggws, off, csr, N);
    k_smm<<<1024, 256, 0, stream>>>(aggws, ha, hb, Wl,                bl,       Wr,               lng + 64,  lnb + 64,  N);
    k_agg<<<2048, 256, 0, stream>>>(hb, aggws, off, csr, N);
    k_smm<<<1024, 256, 0, stream>>>(aggws, hb, ha, Wl + 128 * 64,     bl + 64,  Wr + 64 * 64,     lng + 128, lnb + 128, N);
    k_agg<<<2048, 256, 0, stream>>>(ha, aggws, off, csr, N);
    k_smm<<<1024, 256, 0, stream>>>(aggws, ha, hb, Wl + 2 * 128 * 64, bl + 128, Wr + 2 * 64 * 64, lng + 192, lnb + 192, N);

    k_mlp<<<2048, 256, 0, stream>>>(hb, ha, mW1, mb1, mg, mbn, mW2, mb2, N);
    k_readout<<<NG, 256, 0, stream>>>(ha, x, ptr, rW1, rb1, rg, rbn, rW2, rb2, out);
}